// Round 1
// baseline (1165.979 us; speedup 1.0000x reference)
//
#include <hip/hip_runtime.h>
#include <hip/hip_bf16.h>

#define T_LEN 2048
#define BATCH 2
#define DMODEL 1024
#define NH 16
#define HD 64
#define EMB (NH * HD)   // 1024

// ---------------------------------------------------------------------------
// Fused QKV projection GEMM (fp32):
//   q[t,b,e] = (query[t,b,:] . Wq[e,:] + bq[e]) * 0.125
//   k[t,b,e] =  key  [t,b,:] . Wk[e,:] + bk[e]
//   v[t,b,e] =  value[t,b,:] . Wv[e,:] + bv[e]
// A matrices viewed as (M=4096, K=1024), W = (3072, 1024) row-major.
// Output scattered to (B, H, T, HD) buffers.
// Tile: 128x128x16, 256 threads, 8x8 per thread.
// ---------------------------------------------------------------------------
__global__ __launch_bounds__(256) void qkv_gemm(
    const float* __restrict__ Xq, const float* __restrict__ Xk,
    const float* __restrict__ Xv, const float* __restrict__ W,
    const float* __restrict__ bias,
    float* __restrict__ qbuf, float* __restrict__ kbuf, float* __restrict__ vbuf)
{
    const int bn = blockIdx.x;          // 0..23 (N=3072)
    const int bm = blockIdx.y;          // 0..31 (M=4096)
    const int n0 = bn * 128;
    const int m0 = bm * 128;
    const int which = n0 / EMB;         // 0=q, 1=k, 2=v (tiles never straddle)
    const float* __restrict__ A = (which == 0) ? Xq : (which == 1) ? Xk : Xv;
    float* __restrict__ buf = (which == 0) ? qbuf : (which == 1) ? kbuf : vbuf;
    const float scale = (which == 0) ? 0.125f : 1.0f;

    const int tid = threadIdx.x;
    const int tx = tid & 15;            // n dim
    const int ty = tid >> 4;            // m dim

    __shared__ float As[16][132];
    __shared__ float Bs[16][132];

    float acc[8][8];
    #pragma unroll
    for (int i = 0; i < 8; ++i)
        #pragma unroll
        for (int j = 0; j < 8; ++j) acc[i][j] = 0.f;

    const int lr = tid >> 2;            // 0..63
    const int lc = (tid & 3) * 4;       // 0,4,8,12
    const int K = 1024;

    for (int k0 = 0; k0 < K; k0 += 16) {
        #pragma unroll
        for (int hh = 0; hh < 2; ++hh) {
            const int row = lr + hh * 64;
            const float4 va = *reinterpret_cast<const float4*>(&A[(size_t)(m0 + row) * K + k0 + lc]);
            As[lc + 0][row] = va.x;
            As[lc + 1][row] = va.y;
            As[lc + 2][row] = va.z;
            As[lc + 3][row] = va.w;
            const float4 vb = *reinterpret_cast<const float4*>(&W[(size_t)(n0 + row) * K + k0 + lc]);
            Bs[lc + 0][row] = vb.x;
            Bs[lc + 1][row] = vb.y;
            Bs[lc + 2][row] = vb.z;
            Bs[lc + 3][row] = vb.w;
        }
        __syncthreads();

        #pragma unroll
        for (int k = 0; k < 16; ++k) {
            const float4 a0 = *reinterpret_cast<const float4*>(&As[k][ty * 8]);
            const float4 a1 = *reinterpret_cast<const float4*>(&As[k][ty * 8 + 4]);
            const float4 b0 = *reinterpret_cast<const float4*>(&Bs[k][tx * 8]);
            const float4 b1 = *reinterpret_cast<const float4*>(&Bs[k][tx * 8 + 4]);
            const float av[8] = {a0.x, a0.y, a0.z, a0.w, a1.x, a1.y, a1.z, a1.w};
            const float bv[8] = {b0.x, b0.y, b0.z, b0.w, b1.x, b1.y, b1.z, b1.w};
            #pragma unroll
            for (int i = 0; i < 8; ++i)
                #pragma unroll
                for (int j = 0; j < 8; ++j)
                    acc[i][j] = fmaf(av[i], bv[j], acc[i][j]);
        }
        __syncthreads();
    }

    // epilogue: add bias, scale, scatter to (B,H,T,HD)
    #pragma unroll
    for (int i = 0; i < 8; ++i) {
        const int m = m0 + ty * 8 + i;
        const int t = m >> 1;
        const int b = m & 1;
        #pragma unroll
        for (int j = 0; j < 8; ++j) {
            const int n = n0 + tx * 8 + j;
            const int e = n - which * EMB;
            const int h = e >> 6;
            const int hd = e & 63;
            const float val = (acc[i][j] + bias[n]) * scale;
            buf[(((size_t)b * NH + h) * T_LEN + t) * HD + hd] = val;
        }
    }
}

// ---------------------------------------------------------------------------
// Out projection GEMM (fp32): out[m][n] = A[m][:] . W[n][:] + bias[n]
// A = (4096, 1024) attn output in (T,B,E); W = (1024, 1024) row-major.
// ---------------------------------------------------------------------------
__global__ __launch_bounds__(256) void out_gemm(
    const float* __restrict__ A, const float* __restrict__ W,
    const float* __restrict__ bias, float* __restrict__ out)
{
    const int n0 = blockIdx.x * 128;    // 0..7
    const int m0 = blockIdx.y * 128;    // 0..31
    const int tid = threadIdx.x;
    const int tx = tid & 15;
    const int ty = tid >> 4;

    __shared__ float As[16][132];
    __shared__ float Bs[16][132];

    float acc[8][8];
    #pragma unroll
    for (int i = 0; i < 8; ++i)
        #pragma unroll
        for (int j = 0; j < 8; ++j) acc[i][j] = 0.f;

    const int lr = tid >> 2;
    const int lc = (tid & 3) * 4;
    const int K = 1024;

    for (int k0 = 0; k0 < K; k0 += 16) {
        #pragma unroll
        for (int hh = 0; hh < 2; ++hh) {
            const int row = lr + hh * 64;
            const float4 va = *reinterpret_cast<const float4*>(&A[(size_t)(m0 + row) * K + k0 + lc]);
            As[lc + 0][row] = va.x;
            As[lc + 1][row] = va.y;
            As[lc + 2][row] = va.z;
            As[lc + 3][row] = va.w;
            const float4 vb = *reinterpret_cast<const float4*>(&W[(size_t)(n0 + row) * K + k0 + lc]);
            Bs[lc + 0][row] = vb.x;
            Bs[lc + 1][row] = vb.y;
            Bs[lc + 2][row] = vb.z;
            Bs[lc + 3][row] = vb.w;
        }
        __syncthreads();

        #pragma unroll
        for (int k = 0; k < 16; ++k) {
            const float4 a0 = *reinterpret_cast<const float4*>(&As[k][ty * 8]);
            const float4 a1 = *reinterpret_cast<const float4*>(&As[k][ty * 8 + 4]);
            const float4 b0 = *reinterpret_cast<const float4*>(&Bs[k][tx * 8]);
            const float4 b1 = *reinterpret_cast<const float4*>(&Bs[k][tx * 8 + 4]);
            const float av[8] = {a0.x, a0.y, a0.z, a0.w, a1.x, a1.y, a1.z, a1.w};
            const float bv[8] = {b0.x, b0.y, b0.z, b0.w, b1.x, b1.y, b1.z, b1.w};
            #pragma unroll
            for (int i = 0; i < 8; ++i)
                #pragma unroll
                for (int j = 0; j < 8; ++j)
                    acc[i][j] = fmaf(av[i], bv[j], acc[i][j]);
        }
        __syncthreads();
    }

    #pragma unroll
    for (int i = 0; i < 8; ++i) {
        const int m = m0 + ty * 8 + i;
        #pragma unroll
        for (int j = 0; j < 8; ++j) {
            const int n = n0 + tx * 8 + j;
            out[(size_t)m * DMODEL + n] = acc[i][j] + bias[n];
        }
    }
}

// ---------------------------------------------------------------------------
// Flash attention (fp32, online softmax).
// Block = one (b,h) and 64 query rows. 256 threads (16x16), each thread owns
// a 4x4 block of S / O. KV tiles of 64 rows streamed through LDS.
// ---------------------------------------------------------------------------
__global__ __launch_bounds__(256) void flash_attn(
    const float* __restrict__ Q, const float* __restrict__ K,
    const float* __restrict__ V, const float* __restrict__ mask,
    float* __restrict__ Ao)
{
    const int q0 = blockIdx.x * 64;
    const int bh = blockIdx.y;          // b*NH + h
    const int b = bh >> 4;
    const int h = bh & 15;
    const int tid = threadIdx.x;
    const int tx = tid & 15;
    const int ty = tid >> 4;

    __shared__ float Qt[HD][68];        // Q^T: [hd][i]
    __shared__ float Kt[HD][68];        // K^T: [hd][j]
    __shared__ float Vs[64][68];        // V:   [j][hd]
    __shared__ float Pt[64][68];        // P^T: [j][i]

    // load Q tile transposed
    {
        const int row = tid >> 2;           // 0..63
        const int cg = (tid & 3) * 16;      // 0,16,32,48
        const float* qp = Q + ((size_t)bh * T_LEN + q0) * HD;
        #pragma unroll
        for (int c = 0; c < 4; ++c) {
            const float4 v4 = *reinterpret_cast<const float4*>(&qp[row * HD + cg + c * 4]);
            Qt[cg + c * 4 + 0][row] = v4.x;
            Qt[cg + c * 4 + 1][row] = v4.y;
            Qt[cg + c * 4 + 2][row] = v4.z;
            Qt[cg + c * 4 + 3][row] = v4.w;
        }
    }

    float o[4][4] = {};
    float m_run[4], l_run[4];
    #pragma unroll
    for (int r = 0; r < 4; ++r) { m_run[r] = -1e30f; l_run[r] = 0.f; }

    __syncthreads();

    for (int s0 = 0; s0 < T_LEN; s0 += 64) {
        // stage K (transposed) + V
        {
            const int row = tid >> 2;
            const int cg = (tid & 3) * 16;
            const float* kp = K + ((size_t)bh * T_LEN + s0) * HD;
            const float* vp = V + ((size_t)bh * T_LEN + s0) * HD;
            #pragma unroll
            for (int c = 0; c < 4; ++c) {
                const float4 kv = *reinterpret_cast<const float4*>(&kp[row * HD + cg + c * 4]);
                Kt[cg + c * 4 + 0][row] = kv.x;
                Kt[cg + c * 4 + 1][row] = kv.y;
                Kt[cg + c * 4 + 2][row] = kv.z;
                Kt[cg + c * 4 + 3][row] = kv.w;
                const float4 vv = *reinterpret_cast<const float4*>(&vp[row * HD + cg + c * 4]);
                *reinterpret_cast<float4*>(&Vs[row][cg + c * 4]) = vv;
            }
        }
        __syncthreads();   // B1: K/V staged

        // S = Q K^T: this thread rows ty*4+r, cols tx*4+c
        float s[4][4] = {};
        #pragma unroll 16
        for (int k = 0; k < HD; ++k) {
            const float4 a = *reinterpret_cast<const float4*>(&Qt[k][ty * 4]);
            const float4 bq = *reinterpret_cast<const float4*>(&Kt[k][tx * 4]);
            const float av[4] = {a.x, a.y, a.z, a.w};
            const float bv[4] = {bq.x, bq.y, bq.z, bq.w};
            #pragma unroll
            for (int r = 0; r < 4; ++r)
                #pragma unroll
                for (int c = 0; c < 4; ++c)
                    s[r][c] = fmaf(av[r], bv[c], s[r][c]);
        }

        // + mask
        #pragma unroll
        for (int r = 0; r < 4; ++r) {
            const float4 mv = *reinterpret_cast<const float4*>(
                &mask[(size_t)(q0 + ty * 4 + r) * T_LEN + s0 + tx * 4]);
            s[r][0] += mv.x; s[r][1] += mv.y; s[r][2] += mv.z; s[r][3] += mv.w;
        }

        // online softmax (row reduce across the 16 tx lanes)
        #pragma unroll
        for (int r = 0; r < 4; ++r) {
            float mx = fmaxf(fmaxf(s[r][0], s[r][1]), fmaxf(s[r][2], s[r][3]));
            #pragma unroll
            for (int off = 1; off < 16; off <<= 1)
                mx = fmaxf(mx, __shfl_xor(mx, off, 64));
            const float mn = fmaxf(m_run[r], mx);
            const float alpha = __expf(m_run[r] - mn);
            float rs = 0.f;
            #pragma unroll
            for (int c = 0; c < 4; ++c) { s[r][c] = __expf(s[r][c] - mn); rs += s[r][c]; }
            #pragma unroll
            for (int off = 1; off < 16; off <<= 1)
                rs += __shfl_xor(rs, off, 64);
            l_run[r] = l_run[r] * alpha + rs;
            m_run[r] = mn;
            #pragma unroll
            for (int u = 0; u < 4; ++u) o[r][u] *= alpha;
        }

        // write P^T
        #pragma unroll
        for (int r = 0; r < 4; ++r)
            #pragma unroll
            for (int c = 0; c < 4; ++c)
                Pt[tx * 4 + c][ty * 4 + r] = s[r][c];
        __syncthreads();   // B2: P staged

        // O += P V : this thread rows ty*4+r, hd cols tx*4+u
        #pragma unroll 16
        for (int j = 0; j < 64; ++j) {
            const float4 p = *reinterpret_cast<const float4*>(&Pt[j][ty * 4]);
            const float4 vv = *reinterpret_cast<const float4*>(&Vs[j][tx * 4]);
            const float pv[4] = {p.x, p.y, p.z, p.w};
            const float vvv[4] = {vv.x, vv.y, vv.z, vv.w};
            #pragma unroll
            for (int r = 0; r < 4; ++r)
                #pragma unroll
                for (int u = 0; u < 4; ++u)
                    o[r][u] = fmaf(pv[r], vvv[u], o[r][u]);
        }
        __syncthreads();   // B3: safe to restage K/V/P
    }

    // normalize + write (T,B,E)
    #pragma unroll
    for (int r = 0; r < 4; ++r) {
        const float inv = 1.f / l_run[r];
        const int t = q0 + ty * 4 + r;
        float4 vout;
        vout.x = o[r][0] * inv;
        vout.y = o[r][1] * inv;
        vout.z = o[r][2] * inv;
        vout.w = o[r][3] * inv;
        *reinterpret_cast<float4*>(&Ao[((size_t)t * BATCH + b) * EMB + h * HD + tx * 4]) = vout;
    }
}

extern "C" void kernel_launch(void* const* d_in, const int* in_sizes, int n_in,
                              void* d_out, int out_size, void* d_ws, size_t ws_size,
                              hipStream_t stream) {
    (void)in_sizes; (void)n_in; (void)out_size; (void)ws_size;
    const float* query = (const float*)d_in[0];
    const float* key   = (const float*)d_in[1];
    const float* value = (const float*)d_in[2];
    const float* mask  = (const float*)d_in[3];
    const float* wqkv  = (const float*)d_in[4];
    const float* bqkv  = (const float*)d_in[5];
    const float* wout  = (const float*)d_in[6];
    const float* bout  = (const float*)d_in[7];
    float* out = (float*)d_out;

    float* ws = (float*)d_ws;
    float* qbuf = ws;                         // 4M floats
    float* kbuf = ws + (size_t)4 * 1024 * 1024;
    float* vbuf = ws + (size_t)8 * 1024 * 1024;
    float* abuf = ws + (size_t)12 * 1024 * 1024;

    // 1) QKV projection: M=4096, N=3072, K=1024
    qkv_gemm<<<dim3(24, 32), 256, 0, stream>>>(query, key, value, wqkv, bqkv,
                                               qbuf, kbuf, vbuf);
    // 2) flash attention: grid (T/64, B*H)
    flash_attn<<<dim3(T_LEN / 64, BATCH * NH), 256, 0, stream>>>(qbuf, kbuf, vbuf,
                                                                 mask, abuf);
    // 3) out projection: M=4096, N=1024, K=1024
    out_gemm<<<dim3(8, 32), 256, 0, stream>>>(abuf, wout, bout, out);
}

// Round 5
// 321.005 us; speedup vs baseline: 3.6323x; 3.6323x over previous
//
#include <hip/hip_runtime.h>
#include <hip/hip_bf16.h>

#define T_LEN 2048
#define BATCH 2
#define NH 16
#define HD 64

typedef __attribute__((ext_vector_type(4))) float f32x4;
typedef __attribute__((ext_vector_type(8))) short short8;

__device__ inline void gload16(const __hip_bfloat16* g, __hip_bfloat16* l) {
    __builtin_amdgcn_global_load_lds((const __attribute__((address_space(1))) void*)g,
                                     (__attribute__((address_space(3))) void*)l, 16, 0, 0);
}

// ---------------------------------------------------------------------------
// f32 -> bf16 conversion for all GEMM operands (one pass).
// segments (elements): q 4194304 | k 4194304 | v 4194304 | wqkv 3145728 | wout 1048576
// ---------------------------------------------------------------------------
__global__ __launch_bounds__(256) void cvt_all(
    const float* __restrict__ q, const float* __restrict__ k, const float* __restrict__ v,
    const float* __restrict__ w1, const float* __restrict__ w2,
    __hip_bfloat16* __restrict__ dst)
{
    const size_t i = ((size_t)blockIdx.x * 256 + threadIdx.x) * 8;
    const float* src; size_t off;
    if (i < 4194304)        { src = q;  off = i; }
    else if (i < 8388608)   { src = k;  off = i - 4194304; }
    else if (i < 12582912)  { src = v;  off = i - 8388608; }
    else if (i < 15728640)  { src = w1; off = i - 12582912; }
    else                    { src = w2; off = i - 15728640; }
    const float4 a = *reinterpret_cast<const float4*>(src + off);
    const float4 c = *reinterpret_cast<const float4*>(src + off + 4);
    union { __hip_bfloat16 h[8]; short8 s; } u;
    u.h[0] = __float2bfloat16(a.x); u.h[1] = __float2bfloat16(a.y);
    u.h[2] = __float2bfloat16(a.z); u.h[3] = __float2bfloat16(a.w);
    u.h[4] = __float2bfloat16(c.x); u.h[5] = __float2bfloat16(c.y);
    u.h[6] = __float2bfloat16(c.z); u.h[7] = __float2bfloat16(c.w);
    *reinterpret_cast<short8*>(dst + i) = u.s;
}

// ---------------------------------------------------------------------------
// MFMA GEMM 128x128x32 tile, 4 waves (2x2 of 64x64), bf16 in / f32 acc.
// C[m][n] = sum_k A[m][k]*W[n][k]  (both K-contiguous).
// LDS chunk swizzle: slot p of row holds global chunk g = p ^ ((row>>1)&3).
// Q/K outputs -> (B,H,T,HD); V output -> TRANSPOSED (B,H,HD,T) via per-wave
// LDS transpose (Tt, no cross-wave sharing -> no barrier needed).
// ---------------------------------------------------------------------------
__global__ __launch_bounds__(256) void qkv_gemm_mfma(
    const __hip_bfloat16* __restrict__ Xq, const __hip_bfloat16* __restrict__ Xk,
    const __hip_bfloat16* __restrict__ Xv, const __hip_bfloat16* __restrict__ W,
    const float* __restrict__ bias,
    __hip_bfloat16* __restrict__ qbuf, __hip_bfloat16* __restrict__ kbuf,
    __hip_bfloat16* __restrict__ vbufT)
{
    alignas(16) __shared__ __hip_bfloat16 Asl[128 * 32];
    alignas(16) __shared__ __hip_bfloat16 Bsl[128 * 32];
    alignas(16) __shared__ __hip_bfloat16 Tt[4][64 * 64];   // per-wave V transpose staging
    const int n0 = blockIdx.x * 128;
    const int m0 = blockIdx.y * 128;
    const int which = n0 >> 10;
    const __hip_bfloat16* __restrict__ A = (which == 0) ? Xq : (which == 1) ? Xk : Xv;
    const int tid = threadIdx.x;
    const int lane = tid & 63, wid = tid >> 6;
    const int l15 = lane & 15, lg = lane >> 4;
    const int wr = wid >> 1, wc = wid & 1;

    const int r0 = tid >> 2, p0 = tid & 3;
    const int g0 = p0 ^ ((r0 >> 1) & 3);
    const int r1 = r0 + 64;
    const int g1 = p0 ^ ((r1 >> 1) & 3);
    const __hip_bfloat16* srcA0 = A + (size_t)(m0 + r0) * 1024 + g0 * 8;
    const __hip_bfloat16* srcA1 = A + (size_t)(m0 + r1) * 1024 + g1 * 8;
    const __hip_bfloat16* srcB0 = W + (size_t)(n0 + r0) * 1024 + g0 * 8;
    const __hip_bfloat16* srcB1 = W + (size_t)(n0 + r1) * 1024 + g1 * 8;
    __hip_bfloat16* dA0 = Asl + tid * 8;
    __hip_bfloat16* dA1 = Asl + (tid + 256) * 8;
    __hip_bfloat16* dB0 = Bsl + tid * 8;
    __hip_bfloat16* dB1 = Bsl + (tid + 256) * 8;

    int offA[4], offB[4];
    #pragma unroll
    for (int mi = 0; mi < 4; ++mi) {
        const int row = wr * 64 + mi * 16 + l15;
        offA[mi] = row * 64 + ((lg ^ ((row >> 1) & 3)) << 4);
    }
    #pragma unroll
    for (int ni = 0; ni < 4; ++ni) {
        const int row = wc * 64 + ni * 16 + l15;
        offB[ni] = row * 64 + ((lg ^ ((row >> 1) & 3)) << 4);
    }

    f32x4 acc[4][4] = {};

    for (int k0 = 0; k0 < 1024; k0 += 32) {
        gload16(srcA0 + k0, dA0);
        gload16(srcA1 + k0, dA1);
        gload16(srcB0 + k0, dB0);
        gload16(srcB1 + k0, dB1);
        __syncthreads();
        short8 af[4], bf4[4];
        #pragma unroll
        for (int mi = 0; mi < 4; ++mi)
            af[mi] = *(const short8*)((const char*)Asl + offA[mi]);
        #pragma unroll
        for (int ni = 0; ni < 4; ++ni)
            bf4[ni] = *(const short8*)((const char*)Bsl + offB[ni]);
        #pragma unroll
        for (int mi = 0; mi < 4; ++mi)
            #pragma unroll
            for (int ni = 0; ni < 4; ++ni)
                acc[mi][ni] = __builtin_amdgcn_mfma_f32_16x16x32_bf16(af[mi], bf4[ni], acc[mi][ni], 0, 0, 0);
        __syncthreads();
    }

    if (which != 2) {
        // Q / K epilogue: bias (+scale for Q), scatter to (B,H,T,HD)
        const float scale = (which == 0) ? 0.125f : 1.0f;
        __hip_bfloat16* __restrict__ buf = (which == 0) ? qbuf : kbuf;
        #pragma unroll
        for (int mi = 0; mi < 4; ++mi) {
            #pragma unroll
            for (int r = 0; r < 4; ++r) {
                const int row = m0 + wr * 64 + mi * 16 + lg * 4 + r;
                const int t = row >> 1, b = row & 1;
                #pragma unroll
                for (int ni = 0; ni < 4; ++ni) {
                    const int col = n0 + wc * 64 + ni * 16 + l15;
                    const int e = col & 1023;
                    const int h = e >> 6, d = e & 63;
                    buf[(((size_t)b * NH + h) * T_LEN + t) * HD + d] =
                        __float2bfloat16((acc[mi][ni][r] + bias[col]) * scale);
                }
            }
        }
    } else {
        // V epilogue: per-wave transpose via Tt[wid], write (B,H,HD,T)
        const int hh = (n0 - 2048 + wc * 64) >> 6;     // this wave's head (64-aligned)
        __hip_bfloat16* tw = &Tt[wid][0];
        // Tt layout: [d(64)][b(2)][t'(32)] -> elem = d*64 + b*32 + t'
        #pragma unroll
        for (int mi = 0; mi < 4; ++mi)
            #pragma unroll
            for (int r = 0; r < 4; ++r) {
                const int row = mi * 16 + lg * 4 + r;          // wave-local m (0..63)
                #pragma unroll
                for (int ni = 0; ni < 4; ++ni) {
                    const int col = ni * 16 + l15;             // wave-local d (0..63)
                    tw[col * 64 + (row & 1) * 32 + (row >> 1)] =
                        __float2bfloat16(acc[mi][ni][r] + bias[n0 + wc * 64 + col]);
                }
            }
        // wave-private buffer: intra-wave LDS ordering suffices (no barrier)
        const int t0w = (m0 + wr * 64) >> 1;
        #pragma unroll
        for (int i = 0; i < 8; ++i) {
            const int c = lane + 64 * i;                       // chunk 0..511
            const int d = c >> 3, bb = (c >> 2) & 1, tc = c & 3;
            const short8 v = *(const short8*)(tw + c * 8);
            *(short8*)(vbufT + (((size_t)bb * NH + hh) * HD + d) * T_LEN + t0w + tc * 8) = v;
        }
    }
}

__global__ __launch_bounds__(256) void out_gemm_mfma(
    const __hip_bfloat16* __restrict__ A, const __hip_bfloat16* __restrict__ W,
    const float* __restrict__ bias, float* __restrict__ out)
{
    alignas(16) __shared__ __hip_bfloat16 Asl[128 * 32];
    alignas(16) __shared__ __hip_bfloat16 Bsl[128 * 32];
    const int n0 = blockIdx.x * 128;
    const int m0 = blockIdx.y * 128;
    const int tid = threadIdx.x;
    const int lane = tid & 63, wid = tid >> 6;
    const int l15 = lane & 15, lg = lane >> 4;
    const int wr = wid >> 1, wc = wid & 1;

    const int r0 = tid >> 2, p0 = tid & 3;
    const int g0 = p0 ^ ((r0 >> 1) & 3);
    const int r1 = r0 + 64;
    const int g1 = p0 ^ ((r1 >> 1) & 3);
    const __hip_bfloat16* srcA0 = A + (size_t)(m0 + r0) * 1024 + g0 * 8;
    const __hip_bfloat16* srcA1 = A + (size_t)(m0 + r1) * 1024 + g1 * 8;
    const __hip_bfloat16* srcB0 = W + (size_t)(n0 + r0) * 1024 + g0 * 8;
    const __hip_bfloat16* srcB1 = W + (size_t)(n0 + r1) * 1024 + g1 * 8;
    __hip_bfloat16* dA0 = Asl + tid * 8;
    __hip_bfloat16* dA1 = Asl + (tid + 256) * 8;
    __hip_bfloat16* dB0 = Bsl + tid * 8;
    __hip_bfloat16* dB1 = Bsl + (tid + 256) * 8;

    int offA[4], offB[4];
    #pragma unroll
    for (int mi = 0; mi < 4; ++mi) {
        const int row = wr * 64 + mi * 16 + l15;
        offA[mi] = row * 64 + ((lg ^ ((row >> 1) & 3)) << 4);
    }
    #pragma unroll
    for (int ni = 0; ni < 4; ++ni) {
        const int row = wc * 64 + ni * 16 + l15;
        offB[ni] = row * 64 + ((lg ^ ((row >> 1) & 3)) << 4);
    }

    f32x4 acc[4][4] = {};

    for (int k0 = 0; k0 < 1024; k0 += 32) {
        gload16(srcA0 + k0, dA0);
        gload16(srcA1 + k0, dA1);
        gload16(srcB0 + k0, dB0);
        gload16(srcB1 + k0, dB1);
        __syncthreads();
        short8 af[4], bf4[4];
        #pragma unroll
        for (int mi = 0; mi < 4; ++mi)
            af[mi] = *(const short8*)((const char*)Asl + offA[mi]);
        #pragma unroll
        for (int ni = 0; ni < 4; ++ni)
            bf4[ni] = *(const short8*)((const char*)Bsl + offB[ni]);
        #pragma unroll
        for (int mi = 0; mi < 4; ++mi)
            #pragma unroll
            for (int ni = 0; ni < 4; ++ni)
                acc[mi][ni] = __builtin_amdgcn_mfma_f32_16x16x32_bf16(af[mi], bf4[ni], acc[mi][ni], 0, 0, 0);
        __syncthreads();
    }

    #pragma unroll
    for (int mi = 0; mi < 4; ++mi) {
        #pragma unroll
        for (int r = 0; r < 4; ++r) {
            const int row = m0 + wr * 64 + mi * 16 + lg * 4 + r;
            #pragma unroll
            for (int ni = 0; ni < 4; ++ni) {
                const int col = n0 + wc * 64 + ni * 16 + l15;
                out[(size_t)row * 1024 + col] = acc[mi][ni][r] + bias[col];
            }
        }
    }
}

// ---------------------------------------------------------------------------
// MFMA flash attention. Block = (64 q rows, one bh). 4 waves x 16 q rows.
// KV tile 64. K staged [kv][d], V staged [hd][kv] (from vbufT) — BOTH with
// the XOR chunk swizzle (slot p of row holds chunk g = p ^ (row&7)), both
// consumed as plain swizzled ds_read_b128 B-fragments. P in per-wave LDS.
// ---------------------------------------------------------------------------
__global__ __launch_bounds__(256) void flash_mfma(
    const __hip_bfloat16* __restrict__ Qb, const __hip_bfloat16* __restrict__ Kb,
    const __hip_bfloat16* __restrict__ VTb, const float* __restrict__ mask,
    __hip_bfloat16* __restrict__ Ao)
{
    alignas(16) __shared__ __hip_bfloat16 Kls[64 * 64];
    alignas(16) __shared__ __hip_bfloat16 Vls[64 * 64];
    alignas(16) __shared__ __hip_bfloat16 Pls[4][16 * 64];
    const int q0 = blockIdx.x * 64;
    const int bh = blockIdx.y;
    const int b = bh >> 4, h = bh & 15;
    const int tid = threadIdx.x, lane = tid & 63, wid = tid >> 6;
    const int l15 = lane & 15, lg = lane >> 4;

    // Q fragments (A-operand), held in registers
    const __hip_bfloat16* qrow = Qb + ((size_t)bh * T_LEN + q0 + wid * 16 + l15) * HD;
    const short8 qf0 = *(const short8*)(qrow + lg * 8);
    const short8 qf1 = *(const short8*)(qrow + 32 + lg * 8);

    // staging assignments (2 chunks of 16B each for K and V per thread)
    const int kc0 = tid, kc1 = tid + 256;
    const int kr0 = kc0 >> 3, kg0 = (kc0 & 7) ^ (kr0 & 7);
    const int kr1 = kc1 >> 3, kg1 = (kc1 & 7) ^ (kr1 & 7);
    const __hip_bfloat16* kbase = Kb + (size_t)bh * T_LEN * HD;    // [kv][d]
    const __hip_bfloat16* vbase = VTb + (size_t)bh * HD * T_LEN;   // [hd][t]

    f32x4 o_acc[4] = {};
    float m_run[4], l_run[4];
    #pragma unroll
    for (int r = 0; r < 4; ++r) { m_run[r] = -1e30f; l_run[r] = 0.f; }

    const float* mrow = mask + (size_t)(q0 + wid * 16 + lg * 4) * T_LEN + l15;
    char* pbase = (char*)&Pls[wid][0];

    for (int s0 = 0; s0 < T_LEN; s0 += 64) {
        __syncthreads();
        gload16(kbase + (size_t)(s0 + kr0) * HD + kg0 * 8, Kls + kc0 * 8);
        gload16(kbase + (size_t)(s0 + kr1) * HD + kg1 * 8, Kls + kc1 * 8);
        gload16(vbase + (size_t)kr0 * T_LEN + s0 + kg0 * 8, Vls + kc0 * 8);
        gload16(vbase + (size_t)kr1 * T_LEN + s0 + kg1 * 8, Vls + kc1 * 8);
        __syncthreads();

        // S = Q K^T
        f32x4 sv[4];
        #pragma unroll
        for (int ni = 0; ni < 4; ++ni) {
            const int row = ni * 16 + l15;
            const short8 kf0 = *(const short8*)((const char*)Kls + row * 128 + ((lg ^ (row & 7)) << 4));
            const short8 kf1 = *(const short8*)((const char*)Kls + row * 128 + (((4 + lg) ^ (row & 7)) << 4));
            f32x4 z = {0.f, 0.f, 0.f, 0.f};
            sv[ni] = __builtin_amdgcn_mfma_f32_16x16x32_bf16(qf0, kf0, z, 0, 0, 0);
            sv[ni] = __builtin_amdgcn_mfma_f32_16x16x32_bf16(qf1, kf1, sv[ni], 0, 0, 0);
        }
        // + mask
        #pragma unroll
        for (int ni = 0; ni < 4; ++ni)
            #pragma unroll
            for (int r = 0; r < 4; ++r)
                sv[ni][r] += mrow[(size_t)r * T_LEN + s0 + ni * 16];

        // online softmax (rows lg*4+r, reduce over the 16-lane col group)
        float alpha[4];
        #pragma unroll
        for (int r = 0; r < 4; ++r) {
            float mx = fmaxf(fmaxf(sv[0][r], sv[1][r]), fmaxf(sv[2][r], sv[3][r]));
            mx = fmaxf(mx, __shfl_xor(mx, 1, 64));
            mx = fmaxf(mx, __shfl_xor(mx, 2, 64));
            mx = fmaxf(mx, __shfl_xor(mx, 4, 64));
            mx = fmaxf(mx, __shfl_xor(mx, 8, 64));
            const float mn = fmaxf(m_run[r], mx);
            alpha[r] = __expf(m_run[r] - mn);
            m_run[r] = mn;
            float rs = 0.f;
            #pragma unroll
            for (int ni = 0; ni < 4; ++ni) { sv[ni][r] = __expf(sv[ni][r] - mn); rs += sv[ni][r]; }
            rs += __shfl_xor(rs, 1, 64); rs += __shfl_xor(rs, 2, 64);
            rs += __shfl_xor(rs, 4, 64); rs += __shfl_xor(rs, 8, 64);
            l_run[r] = l_run[r] * alpha[r] + rs;
        }
        #pragma unroll
        for (int ni = 0; ni < 4; ++ni) {
            o_acc[ni][0] *= alpha[0]; o_acc[ni][1] *= alpha[1];
            o_acc[ni][2] *= alpha[2]; o_acc[ni][3] *= alpha[3];
        }

        // P -> bf16 -> per-wave LDS (pair kv cols via shfl_xor(1); even lanes
        // write rows r=0,1 of their lg group, odd lanes rows 2,3)
        const int rb = (l15 & 1) * 2;
        #pragma unroll
        for (int ni = 0; ni < 4; ++ni) {
            const float x0 = __shfl_xor(sv[ni][0], 1, 64);
            const float x1 = __shfl_xor(sv[ni][1], 1, 64);
            const float x2 = __shfl_xor(sv[ni][2], 1, 64);
            const float x3 = __shfl_xor(sv[ni][3], 1, 64);
            union { __hip_bfloat16 hh[2]; unsigned u; } w0, w1;
            if (rb == 0) {
                w0.hh[0] = __float2bfloat16(sv[ni][0]); w0.hh[1] = __float2bfloat16(x0);
                w1.hh[0] = __float2bfloat16(sv[ni][1]); w1.hh[1] = __float2bfloat16(x1);
            } else {
                w0.hh[0] = __float2bfloat16(x2); w0.hh[1] = __float2bfloat16(sv[ni][2]);
                w1.hh[0] = __float2bfloat16(x3); w1.hh[1] = __float2bfloat16(sv[ni][3]);
            }
            const int qw = lg * 4 + rb;
            const int kvb = ni * 16 + (l15 & ~1);
            const int ch = kvb >> 3, wb = (kvb & 7) * 2;
            *(unsigned*)(pbase + qw * 128 + ((ch ^ (qw & 7)) << 4) + wb) = w0.u;
            *(unsigned*)(pbase + (qw + 1) * 128 + ((ch ^ ((qw + 1) & 7)) << 4) + wb) = w1.u;
        }

        // O += P V  (Vt rows = hd, cols = kv; plain swizzled b128 B-fragments)
        #pragma unroll
        for (int ks = 0; ks < 2; ++ks) {
            const short8 pa = *(const short8*)(pbase + l15 * 128 + (((4 * ks + lg) ^ (l15 & 7)) << 4));
            #pragma unroll
            for (int ni = 0; ni < 4; ++ni) {
                const int row = ni * 16 + l15;
                const short8 vb = *(const short8*)((const char*)Vls + row * 128 + (((ks * 4 + lg) ^ (row & 7)) << 4));
                o_acc[ni] = __builtin_amdgcn_mfma_f32_16x16x32_bf16(pa, vb, o_acc[ni], 0, 0, 0);
            }
        }
    }

    // normalize + store (T,B,E) bf16
    #pragma unroll
    for (int r = 0; r < 4; ++r) {
        const float inv = 1.f / l_run[r];
        const int t = q0 + wid * 16 + lg * 4 + r;
        #pragma unroll
        for (int ni = 0; ni < 4; ++ni)
            Ao[((size_t)t * BATCH + b) * 1024 + h * HD + ni * 16 + l15] =
                __float2bfloat16(o_acc[ni][r] * inv);
    }
}

extern "C" void kernel_launch(void* const* d_in, const int* in_sizes, int n_in,
                              void* d_out, int out_size, void* d_ws, size_t ws_size,
                              hipStream_t stream) {
    (void)in_sizes; (void)n_in; (void)out_size; (void)ws_size;
    const float* query = (const float*)d_in[0];
    const float* key   = (const float*)d_in[1];
    const float* value = (const float*)d_in[2];
    const float* mask  = (const float*)d_in[3];
    const float* wqkv  = (const float*)d_in[4];
    const float* bqkv  = (const float*)d_in[5];
    const float* wout  = (const float*)d_in[6];
    const float* bout  = (const float*)d_in[7];
    float* out = (float*)d_out;

    __hip_bfloat16* cvt = (__hip_bfloat16*)d_ws;
    __hip_bfloat16* xq    = cvt;                    // 4194304
    __hip_bfloat16* xk    = cvt + 4194304;          // 4194304
    __hip_bfloat16* xv    = cvt + 8388608;          // 4194304
    __hip_bfloat16* w1    = cvt + 12582912;         // 3145728
    __hip_bfloat16* w2    = cvt + 15728640;         // 1048576
    __hip_bfloat16* qbuf  = cvt + 16777216;         // 4194304
    __hip_bfloat16* kbuf  = qbuf + 4194304;         // 4194304
    __hip_bfloat16* vbufT = kbuf + 4194304;         // 4194304  (B,H,HD,T)
    __hip_bfloat16* abuf  = xq;                     // reuse: xq dead after qkv_gemm

    cvt_all<<<8192, 256, 0, stream>>>(query, key, value, wqkv, wout, cvt);
    qkv_gemm_mfma<<<dim3(24, 32), 256, 0, stream>>>(xq, xk, xv, w1, bqkv, qbuf, kbuf, vbufT);
    flash_mfma<<<dim3(32, 32), 256, 0, stream>>>(qbuf, kbuf, vbufT, mask, abuf);
    out_gemm_mfma<<<dim3(8, 32), 256, 0, stream>>>(abuf, w2, bout, out);
}

// Round 7
// 294.763 us; speedup vs baseline: 3.9557x; 1.0890x over previous
//
#include <hip/hip_runtime.h>
#include <hip/hip_bf16.h>

#define T_LEN 2048
#define BATCH 2
#define NH 16
#define HD 64
#define LOG2E 1.44269504f

typedef __attribute__((ext_vector_type(4))) float f32x4;
typedef __attribute__((ext_vector_type(16))) float f32x16;
typedef __attribute__((ext_vector_type(8))) short short8;

#define MFMA32(a, b, c) __builtin_amdgcn_mfma_f32_32x32x16_bf16(a, b, c, 0, 0, 0)
#define CVTPK(d, lo, hi) asm("v_cvt_pk_bf16_f32 %0, %1, %2" : "=v"(d) : "v"(lo), "v"(hi))
#define PSWAP(x, y) asm("v_permlane32_swap_b32 %0, %1" : "+v"(x), "+v"(y))

__device__ inline void gload16(const __hip_bfloat16* g, __hip_bfloat16* l) {
    __builtin_amdgcn_global_load_lds((const __attribute__((address_space(1))) void*)g,
                                     (__attribute__((address_space(3))) void*)l, 16, 0, 0);
}

// ---------------------------------------------------------------------------
// f32 -> bf16 conversion for all GEMM operands (one pass).
// ---------------------------------------------------------------------------
__global__ __launch_bounds__(256) void cvt_all(
    const float* __restrict__ q, const float* __restrict__ k, const float* __restrict__ v,
    const float* __restrict__ w1, const float* __restrict__ w2,
    __hip_bfloat16* __restrict__ dst)
{
    const size_t i = ((size_t)blockIdx.x * 256 + threadIdx.x) * 8;
    const float* src; size_t off;
    if (i < 4194304)        { src = q;  off = i; }
    else if (i < 8388608)   { src = k;  off = i - 4194304; }
    else if (i < 12582912)  { src = v;  off = i - 8388608; }
    else if (i < 15728640)  { src = w1; off = i - 12582912; }
    else                    { src = w2; off = i - 15728640; }
    const float4 a = *reinterpret_cast<const float4*>(src + off);
    const float4 c = *reinterpret_cast<const float4*>(src + off + 4);
    union { __hip_bfloat16 h[8]; short8 s; } u;
    u.h[0] = __float2bfloat16(a.x); u.h[1] = __float2bfloat16(a.y);
    u.h[2] = __float2bfloat16(a.z); u.h[3] = __float2bfloat16(a.w);
    u.h[4] = __float2bfloat16(c.x); u.h[5] = __float2bfloat16(c.y);
    u.h[6] = __float2bfloat16(c.z); u.h[7] = __float2bfloat16(c.w);
    *reinterpret_cast<short8*>(dst + i) = u.s;
}

// ---------------------------------------------------------------------------
// mask^T, pre-scaled by log2(e) (exp2 softmax path). 64x64 f32 LDS tiles.
// ---------------------------------------------------------------------------
__global__ __launch_bounds__(256) void transpose_mask(
    const float* __restrict__ mask, float* __restrict__ maskT)
{
    __shared__ float tile[64][65];
    const int t0 = blockIdx.x * 64, s0 = blockIdx.y * 64;
    const int x = threadIdx.x & 63, y0 = threadIdx.x >> 6;
    #pragma unroll
    for (int p = 0; p < 16; ++p) {
        const int r = p * 4 + y0;
        tile[r][x] = mask[(size_t)(t0 + r) * T_LEN + s0 + x] * LOG2E;
    }
    __syncthreads();
    #pragma unroll
    for (int p = 0; p < 16; ++p) {
        const int r = p * 4 + y0;
        maskT[(size_t)(s0 + r) * T_LEN + t0 + x] = tile[x][r];
    }
}

// ---------------------------------------------------------------------------
// MFMA GEMM 128x128x32 tile, 4 waves (2x2 of 64x64), bf16 in / f32 acc.
// Q scale folds 1/sqrt(HD) AND log2(e) (softmax uses exp2).
// ---------------------------------------------------------------------------
__global__ __launch_bounds__(256) void qkv_gemm_mfma(
    const __hip_bfloat16* __restrict__ Xq, const __hip_bfloat16* __restrict__ Xk,
    const __hip_bfloat16* __restrict__ Xv, const __hip_bfloat16* __restrict__ W,
    const float* __restrict__ bias,
    __hip_bfloat16* __restrict__ qbuf, __hip_bfloat16* __restrict__ kbuf,
    __hip_bfloat16* __restrict__ vbufT)
{
    alignas(16) __shared__ __hip_bfloat16 Asl[128 * 32];
    alignas(16) __shared__ __hip_bfloat16 Bsl[128 * 32];
    alignas(16) __shared__ __hip_bfloat16 Tt[4][64 * 64];
    const int n0 = blockIdx.x * 128;
    const int m0 = blockIdx.y * 128;
    const int which = n0 >> 10;
    const __hip_bfloat16* __restrict__ A = (which == 0) ? Xq : (which == 1) ? Xk : Xv;
    const int tid = threadIdx.x;
    const int lane = tid & 63, wid = tid >> 6;
    const int l15 = lane & 15, lg = lane >> 4;
    const int wr = wid >> 1, wc = wid & 1;

    const int r0 = tid >> 2, p0 = tid & 3;
    const int g0 = p0 ^ ((r0 >> 1) & 3);
    const int r1 = r0 + 64;
    const int g1 = p0 ^ ((r1 >> 1) & 3);
    const __hip_bfloat16* srcA0 = A + (size_t)(m0 + r0) * 1024 + g0 * 8;
    const __hip_bfloat16* srcA1 = A + (size_t)(m0 + r1) * 1024 + g1 * 8;
    const __hip_bfloat16* srcB0 = W + (size_t)(n0 + r0) * 1024 + g0 * 8;
    const __hip_bfloat16* srcB1 = W + (size_t)(n0 + r1) * 1024 + g1 * 8;
    __hip_bfloat16* dA0 = Asl + tid * 8;
    __hip_bfloat16* dA1 = Asl + (tid + 256) * 8;
    __hip_bfloat16* dB0 = Bsl + tid * 8;
    __hip_bfloat16* dB1 = Bsl + (tid + 256) * 8;

    int offA[4], offB[4];
    #pragma unroll
    for (int mi = 0; mi < 4; ++mi) {
        const int row = wr * 64 + mi * 16 + l15;
        offA[mi] = row * 64 + ((lg ^ ((row >> 1) & 3)) << 4);
    }
    #pragma unroll
    for (int ni = 0; ni < 4; ++ni) {
        const int row = wc * 64 + ni * 16 + l15;
        offB[ni] = row * 64 + ((lg ^ ((row >> 1) & 3)) << 4);
    }

    f32x4 acc[4][4] = {};

    for (int k0 = 0; k0 < 1024; k0 += 32) {
        gload16(srcA0 + k0, dA0);
        gload16(srcA1 + k0, dA1);
        gload16(srcB0 + k0, dB0);
        gload16(srcB1 + k0, dB1);
        __syncthreads();
        short8 af[4], bf4[4];
        #pragma unroll
        for (int mi = 0; mi < 4; ++mi)
            af[mi] = *(const short8*)((const char*)Asl + offA[mi]);
        #pragma unroll
        for (int ni = 0; ni < 4; ++ni)
            bf4[ni] = *(const short8*)((const char*)Bsl + offB[ni]);
        #pragma unroll
        for (int mi = 0; mi < 4; ++mi)
            #pragma unroll
            for (int ni = 0; ni < 4; ++ni)
                acc[mi][ni] = __builtin_amdgcn_mfma_f32_16x16x32_bf16(af[mi], bf4[ni], acc[mi][ni], 0, 0, 0);
        __syncthreads();
    }

    if (which != 2) {
        const float scale = (which == 0) ? 0.125f * LOG2E : 1.0f;
        __hip_bfloat16* __restrict__ buf = (which == 0) ? qbuf : kbuf;
        #pragma unroll
        for (int mi = 0; mi < 4; ++mi) {
            #pragma unroll
            for (int r = 0; r < 4; ++r) {
                const int row = m0 + wr * 64 + mi * 16 + lg * 4 + r;
                const int t = row >> 1, b = row & 1;
                #pragma unroll
                for (int ni = 0; ni < 4; ++ni) {
                    const int col = n0 + wc * 64 + ni * 16 + l15;
                    const int e = col & 1023;
                    const int h = e >> 6, d = e & 63;
                    buf[(((size_t)b * NH + h) * T_LEN + t) * HD + d] =
                        __float2bfloat16((acc[mi][ni][r] + bias[col]) * scale);
                }
            }
        }
    } else {
        const int hh = (n0 - 2048 + wc * 64) >> 6;
        __hip_bfloat16* tw = &Tt[wid][0];
        #pragma unroll
        for (int mi = 0; mi < 4; ++mi)
            #pragma unroll
            for (int r = 0; r < 4; ++r) {
                const int row = mi * 16 + lg * 4 + r;
                #pragma unroll
                for (int ni = 0; ni < 4; ++ni) {
                    const int col = ni * 16 + l15;
                    tw[col * 64 + (row & 1) * 32 + (row >> 1)] =
                        __float2bfloat16(acc[mi][ni][r] + bias[n0 + wc * 64 + col]);
                }
            }
        const int t0w = (m0 + wr * 64) >> 1;
        #pragma unroll
        for (int i = 0; i < 8; ++i) {
            const int c = lane + 64 * i;
            const int d = c >> 3, bb = (c >> 2) & 1, tc = c & 3;
            const short8 v = *(const short8*)(tw + c * 8);
            *(short8*)(vbufT + (((size_t)bb * NH + hh) * HD + d) * T_LEN + t0w + tc * 8) = v;
        }
    }
}

__global__ __launch_bounds__(256) void out_gemm_mfma(
    const __hip_bfloat16* __restrict__ A, const __hip_bfloat16* __restrict__ W,
    const float* __restrict__ bias, float* __restrict__ out)
{
    alignas(16) __shared__ __hip_bfloat16 Asl[128 * 32];
    alignas(16) __shared__ __hip_bfloat16 Bsl[128 * 32];
    const int n0 = blockIdx.x * 128;
    const int m0 = blockIdx.y * 128;
    const int tid = threadIdx.x;
    const int lane = tid & 63, wid = tid >> 6;
    const int l15 = lane & 15, lg = lane >> 4;
    const int wr = wid >> 1, wc = wid & 1;

    const int r0 = tid >> 2, p0 = tid & 3;
    const int g0 = p0 ^ ((r0 >> 1) & 3);
    const int r1 = r0 + 64;
    const int g1 = p0 ^ ((r1 >> 1) & 3);
    const __hip_bfloat16* srcA0 = A + (size_t)(m0 + r0) * 1024 + g0 * 8;
    const __hip_bfloat16* srcA1 = A + (size_t)(m0 + r1) * 1024 + g1 * 8;
    const __hip_bfloat16* srcB0 = W + (size_t)(n0 + r0) * 1024 + g0 * 8;
    const __hip_bfloat16* srcB1 = W + (size_t)(n0 + r1) * 1024 + g1 * 8;
    __hip_bfloat16* dA0 = Asl + tid * 8;
    __hip_bfloat16* dA1 = Asl + (tid + 256) * 8;
    __hip_bfloat16* dB0 = Bsl + tid * 8;
    __hip_bfloat16* dB1 = Bsl + (tid + 256) * 8;

    int offA[4], offB[4];
    #pragma unroll
    for (int mi = 0; mi < 4; ++mi) {
        const int row = wr * 64 + mi * 16 + l15;
        offA[mi] = row * 64 + ((lg ^ ((row >> 1) & 3)) << 4);
    }
    #pragma unroll
    for (int ni = 0; ni < 4; ++ni) {
        const int row = wc * 64 + ni * 16 + l15;
        offB[ni] = row * 64 + ((lg ^ ((row >> 1) & 3)) << 4);
    }

    f32x4 acc[4][4] = {};

    for (int k0 = 0; k0 < 1024; k0 += 32) {
        gload16(srcA0 + k0, dA0);
        gload16(srcA1 + k0, dA1);
        gload16(srcB0 + k0, dB0);
        gload16(srcB1 + k0, dB1);
        __syncthreads();
        short8 af[4], bf4[4];
        #pragma unroll
        for (int mi = 0; mi < 4; ++mi)
            af[mi] = *(const short8*)((const char*)Asl + offA[mi]);
        #pragma unroll
        for (int ni = 0; ni < 4; ++ni)
            bf4[ni] = *(const short8*)((const char*)Bsl + offB[ni]);
        #pragma unroll
        for (int mi = 0; mi < 4; ++mi)
            #pragma unroll
            for (int ni = 0; ni < 4; ++ni)
                acc[mi][ni] = __builtin_amdgcn_mfma_f32_16x16x32_bf16(af[mi], bf4[ni], acc[mi][ni], 0, 0, 0);
        __syncthreads();
    }

    #pragma unroll
    for (int mi = 0; mi < 4; ++mi) {
        #pragma unroll
        for (int r = 0; r < 4; ++r) {
            const int row = m0 + wr * 64 + mi * 16 + lg * 4 + r;
            #pragma unroll
            for (int ni = 0; ni < 4; ++ni) {
                const int col = n0 + wc * 64 + ni * 16 + l15;
                out[(size_t)row * 1024 + col] = acc[mi][ni][r] + bias[col];
            }
        }
    }
}

// ---------------------------------------------------------------------------
// Flash attention v2: swapped-operand 32x32 MFMA, in-register softmax.
// Block = (128 q rows, one bh), 4 waves x 32 q rows. KV tile 64.
// S^T = mfma(K, Q): lane owns q=lane&31, kv rows (reg&3)+8*(reg>>2)+4*(lane>>5)
// per 32-kv chunk. Softmax: in-lane tree + ONE shfl_xor(32). P^T -> bf16 via
// v_cvt_pk_bf16_f32 + v_permlane32_swap -> PV B-frags in registers (no P LDS).
// O^T = mfma(V^T, P^T) accumulated in registers. exp2 domain (log2e folded
// into Q scale and maskT).
// ---------------------------------------------------------------------------
__global__ __launch_bounds__(256) void flash_mfma(
    const __hip_bfloat16* __restrict__ Qb, const __hip_bfloat16* __restrict__ Kb,
    const __hip_bfloat16* __restrict__ VTb, const float* __restrict__ maskT,
    __hip_bfloat16* __restrict__ Ao)
{
    alignas(16) __shared__ __hip_bfloat16 Kls[64 * 64];
    alignas(16) __shared__ __hip_bfloat16 Vls[64 * 64];
    const int q0 = blockIdx.x * 128;
    const int bh = blockIdx.y;
    const int b = bh >> 4, h16 = bh & 15;
    const int tid = threadIdx.x, lane = tid & 63, wq = tid >> 6;
    const int l31 = lane & 31, hl = lane >> 5;

    const int qg = q0 + wq * 32 + l31;

    // Q B-frags in registers: qf[c] = Q[qg][c*16 + hl*8 .. +7]
    const __hip_bfloat16* qrow = Qb + ((size_t)bh * T_LEN + qg) * HD + hl * 8;
    short8 qf[4];
    #pragma unroll
    for (int c = 0; c < 4; ++c) qf[c] = *(const short8*)(qrow + c * 16);

    // staging (16B chunks; slot p of row holds global chunk g = p ^ (row&7))
    const int kc0 = tid, kc1 = tid + 256;
    const int kr0 = kc0 >> 3, kg0 = (kc0 & 7) ^ (kr0 & 7);
    const int kr1 = kc1 >> 3, kg1 = (kc1 & 7) ^ (kr1 & 7);
    const __hip_bfloat16* kbase = Kb + (size_t)bh * T_LEN * HD;   // [kv][hd]
    const __hip_bfloat16* vbase = VTb + (size_t)bh * HD * T_LEN;  // [hd][t]

    f32x16 oa0 = {}, oa1 = {};
    float m_run = -1e30f, l_run = 0.f;
    const int swz7 = l31 & 7;

    for (int s0 = 0; s0 < T_LEN; s0 += 64) {
        __syncthreads();
        gload16(kbase + (size_t)(s0 + kr0) * HD + kg0 * 8, Kls + kc0 * 8);
        gload16(kbase + (size_t)(s0 + kr1) * HD + kg1 * 8, Kls + kc1 * 8);
        gload16(vbase + (size_t)kr0 * T_LEN + s0 + kg0 * 8, Vls + kc0 * 8);
        gload16(vbase + (size_t)kr1 * T_LEN + s0 + kg1 * 8, Vls + kc1 * 8);

        // mask rows for this tile (coalesced; independent of LDS)
        float mr[32];
        {
            const float* mp = maskT + (size_t)(s0 + 4 * hl) * T_LEN + qg;
            #pragma unroll
            for (int kvc = 0; kvc < 2; ++kvc)
                #pragma unroll
                for (int i = 0; i < 16; ++i)
                    mr[kvc * 16 + i] =
                        mp[(size_t)((i & 3) + 8 * (i >> 2) + kvc * 32) * T_LEN];
        }
        __syncthreads();

        // S^T = K . Q^T
        f32x16 s0v = {}, s1v = {};
        #pragma unroll
        for (int c = 0; c < 4; ++c) {
            const int byte0 = l31 * 128 + (((c * 2 + hl) ^ swz7) << 4);
            const short8 ka0 = *(const short8*)((const char*)Kls + byte0);
            const short8 ka1 = *(const short8*)((const char*)Kls + byte0 + 32 * 128);
            s0v = MFMA32(ka0, qf[c], s0v);
            s1v = MFMA32(ka1, qf[c], s1v);
        }
        #pragma unroll
        for (int i = 0; i < 16; ++i) { s0v[i] += mr[i]; s1v[i] += mr[16 + i]; }

        // row max: in-lane tree + one cross-half shuffle
        float t8[8];
        #pragma unroll
        for (int i = 0; i < 8; ++i)
            t8[i] = fmaxf(fmaxf(s0v[i], s0v[i + 8]), fmaxf(s1v[i], s1v[i + 8]));
        float t4a = fmaxf(t8[0], t8[4]), t4b = fmaxf(t8[1], t8[5]);
        float t4c = fmaxf(t8[2], t8[6]), t4d = fmaxf(t8[3], t8[7]);
        float mx = fmaxf(fmaxf(t4a, t4b), fmaxf(t4c, t4d));
        mx = fmaxf(mx, __shfl_xor(mx, 32, 64));
        const float mn = fmaxf(m_run, mx);
        const float alpha = exp2f(m_run - mn);
        m_run = mn;
        #pragma unroll
        for (int i = 0; i < 16; ++i) {
            s0v[i] = exp2f(s0v[i] - mn);
            s1v[i] = exp2f(s1v[i] - mn);
        }
        // row sum
        float u8[8];
        #pragma unroll
        for (int i = 0; i < 8; ++i)
            u8[i] = (s0v[i] + s0v[i + 8]) + (s1v[i] + s1v[i + 8]);
        float rs = ((u8[0] + u8[4]) + (u8[1] + u8[5])) +
                   ((u8[2] + u8[6]) + (u8[3] + u8[7]));
        rs += __shfl_xor(rs, 32, 64);
        l_run = l_run * alpha + rs;
        #pragma unroll
        for (int i = 0; i < 16; ++i) { oa0[i] *= alpha; oa1[i] *= alpha; }

        // P^T -> bf16 B-frags (registers only)
        unsigned a0, a1, a2, a3, a4, a5, a6, a7;
        unsigned c0, c1, c2, c3, c4, c5, c6, c7;
        CVTPK(a0, s0v[0], s0v[1]);   CVTPK(a1, s0v[2], s0v[3]);
        CVTPK(a2, s0v[4], s0v[5]);   CVTPK(a3, s0v[6], s0v[7]);
        CVTPK(a4, s0v[8], s0v[9]);   CVTPK(a5, s0v[10], s0v[11]);
        CVTPK(a6, s0v[12], s0v[13]); CVTPK(a7, s0v[14], s0v[15]);
        CVTPK(c0, s1v[0], s1v[1]);   CVTPK(c1, s1v[2], s1v[3]);
        CVTPK(c2, s1v[4], s1v[5]);   CVTPK(c3, s1v[6], s1v[7]);
        CVTPK(c4, s1v[8], s1v[9]);   CVTPK(c5, s1v[10], s1v[11]);
        CVTPK(c6, s1v[12], s1v[13]); CVTPK(c7, s1v[14], s1v[15]);
        PSWAP(a0, a2); PSWAP(a1, a3); PSWAP(a4, a6); PSWAP(a5, a7);
        PSWAP(c0, c2); PSWAP(c1, c3); PSWAP(c4, c6); PSWAP(c5, c7);
        union { unsigned u[4]; short8 s; } pf0, pf1, pf2, pf3;
        pf0.u[0] = a0; pf0.u[1] = a1; pf0.u[2] = a2; pf0.u[3] = a3;
        pf1.u[0] = a4; pf1.u[1] = a5; pf1.u[2] = a6; pf1.u[3] = a7;
        pf2.u[0] = c0; pf2.u[1] = c1; pf2.u[2] = c2; pf2.u[3] = c3;
        pf3.u[0] = c4; pf3.u[1] = c5; pf3.u[2] = c6; pf3.u[3] = c7;

        // O^T += V^T . P^T
        #pragma unroll
        for (int kc = 0; kc < 4; ++kc) {
            const int byte0 = l31 * 128 + (((kc * 2 + hl) ^ swz7) << 4);
            const short8 va0 = *(const short8*)((const char*)Vls + byte0);
            const short8 va1 = *(const short8*)((const char*)Vls + byte0 + 32 * 128);
            const short8 pf = (kc == 0) ? pf0.s : (kc == 1) ? pf1.s : (kc == 2) ? pf2.s : pf3.s;
            oa0 = MFMA32(va0, pf, oa0);
            oa1 = MFMA32(va1, pf, oa1);
        }
    }

    // epilogue: O^T lane q=qg, hd = 8a + 4*hl + e (oa0), +32 (oa1) -> (T,B,E)
    const float inv = 1.f / l_run;
    __hip_bfloat16* aop = Ao + ((size_t)qg * BATCH + b) * 1024 + h16 * HD;
    #pragma unroll
    for (int a = 0; a < 4; ++a) {
        union { __hip_bfloat16 hh[4]; short4 s4; } u0, u1;
        #pragma unroll
        for (int e = 0; e < 4; ++e) {
            u0.hh[e] = __float2bfloat16(oa0[a * 4 + e] * inv);
            u1.hh[e] = __float2bfloat16(oa1[a * 4 + e] * inv);
        }
        *(short4*)(aop + a * 8 + 4 * hl) = u0.s4;
        *(short4*)(aop + 32 + a * 8 + 4 * hl) = u1.s4;
    }
}

extern "C" void kernel_launch(void* const* d_in, const int* in_sizes, int n_in,
                              void* d_out, int out_size, void* d_ws, size_t ws_size,
                              hipStream_t stream) {
    (void)in_sizes; (void)n_in; (void)out_size; (void)ws_size;
    const float* query = (const float*)d_in[0];
    const float* key   = (const float*)d_in[1];
    const float* value = (const float*)d_in[2];
    const float* mask  = (const float*)d_in[3];
    const float* wqkv  = (const float*)d_in[4];
    const float* bqkv  = (const float*)d_in[5];
    const float* wout  = (const float*)d_in[6];
    const float* bout  = (const float*)d_in[7];
    float* out = (float*)d_out;

    __hip_bfloat16* cvt = (__hip_bfloat16*)d_ws;
    __hip_bfloat16* xq    = cvt;                    // 4194304 elems
    __hip_bfloat16* xk    = cvt + 4194304;          // 4194304
    __hip_bfloat16* xv    = cvt + 8388608;          // 4194304
    __hip_bfloat16* w1    = cvt + 12582912;         // 3145728
    __hip_bfloat16* w2    = cvt + 15728640;         // 1048576
    __hip_bfloat16* qbuf  = cvt + 16777216;         // 4194304
    __hip_bfloat16* kbuf  = qbuf + 4194304;         // 4194304
    __hip_bfloat16* vbufT = kbuf + 4194304;         // 4194304  (B,H,HD,T)
    float* maskT = (float*)xk;                      // 16MB over dead xk+xv
    __hip_bfloat16* abuf  = xq;                     // reuse: xq dead after qkv_gemm

    cvt_all<<<8192, 256, 0, stream>>>(query, key, value, wqkv, wout, cvt);
    qkv_gemm_mfma<<<dim3(24, 32), 256, 0, stream>>>(xq, xk, xv, w1, bqkv, qbuf, kbuf, vbufT);
    transpose_mask<<<dim3(32, 32), 256, 0, stream>>>(mask, maskT);
    flash_mfma<<<dim3(16, 32), 256, 0, stream>>>(qbuf, kbuf, vbufT, maskT, abuf);
    out_gemm_mfma<<<dim3(8, 32), 256, 0, stream>>>(abuf, w2, bout, out);
}